// Round 8
// baseline (241.979 us; speedup 1.0000x reference)
//
#include <hip/hip_runtime.h>
#include <hip/hip_bf16.h>

#define NSP 4096      // D*H*W
#define CH 256
#define NB 2
#define NG 8
#define CPG 32        // channels per group
#define NHD 4         // heads
#define HDIM 64       // head dim

typedef unsigned short u16;
typedef unsigned int u32;
typedef __attribute__((ext_vector_type(8))) short bf16x8;
typedef __attribute__((ext_vector_type(4))) float f32x4;

#define MFMA __builtin_amdgcn_mfma_f32_16x16x32_bf16

__device__ __forceinline__ u16 f2bf(float f) {
    u32 i = __float_as_uint(f);
    u32 r = (i + 0x7FFFu + ((i >> 16) & 1u)) >> 16;   // round-nearest-even
    return (u16)r;
}

// ---------------- fp32 -> bf16 weight conversion (qkv_w ++ proj_w) ----------------
__global__ __launch_bounds__(256) void wconv2(const float* __restrict__ qw,
                                              const float* __restrict__ pw,
                                              u16* __restrict__ wqb,
                                              u16* __restrict__ wpb) {
    int i = (blockIdx.x * 256 + threadIdx.x) * 4;
    const float* src; u16* dst;
    if (i < 3 * CH * CH) { src = qw + i; dst = wqb + i; }
    else { src = pw + (i - 3 * CH * CH); dst = wpb + (i - 3 * CH * CH); }
    float4 v = *(const float4*)src;
    ushort4 o;
    o.x = f2bf(v.x); o.y = f2bf(v.y); o.z = f2bf(v.z); o.w = f2bf(v.w);
    *(ushort4*)dst = o;
}

// ---------------- GroupNorm partial stats: grid (16 bg, 16 chunks) ----------------
__global__ __launch_bounds__(256) void gn_part(const float* __restrict__ x,
                                               float* __restrict__ partial) {
    const int bg = blockIdx.x, chunk = blockIdx.y;
    const float* p = x + (size_t)bg * (CPG * NSP) + chunk * 8192;
    float s = 0.f, ss = 0.f;
    for (int i = threadIdx.x; i < 2048; i += 256) {   // 8192 floats
        float4 u = ((const float4*)p)[i];
        s += u.x + u.y + u.z + u.w;
        ss += u.x * u.x + u.y * u.y + u.z * u.z + u.w * u.w;
    }
    for (int off = 32; off > 0; off >>= 1) {
        s += __shfl_down(s, off);
        ss += __shfl_down(ss, off);
    }
    __shared__ float red[4][2];
    const int wv = threadIdx.x >> 6;
    if ((threadIdx.x & 63) == 0) { red[wv][0] = s; red[wv][1] = ss; }
    __syncthreads();
    if (threadIdx.x == 0) {
        float ts = red[0][0] + red[1][0] + red[2][0] + red[3][0];
        float tq = red[0][1] + red[1][1] + red[2][1] + red[3][1];
        partial[(bg * 16 + chunk) * 2]     = ts;
        partial[(bg * 16 + chunk) * 2 + 1] = tq;
    }
}

// ------- GroupNorm apply + transpose: x[b][c][n] fp32 -> xnT[b][n][c] bf16 -------
__global__ __launch_bounds__(256) void gn_apply_t(const float* __restrict__ x,
                                                  const float* __restrict__ partial,
                                                  const float* __restrict__ w,
                                                  const float* __restrict__ b,
                                                  u16* __restrict__ xnT) {
    __shared__ u16 T[64][72];   // [n][c], pitch 144 B
    const int n0 = blockIdx.x * 64, c0 = blockIdx.y * 64, bb = blockIdx.z;
    const int t = threadIdx.x;
    const int rc = t & 63;          // channel within tile
    const int g  = t >> 6;          // n-chunk group of 16
    const int c  = c0 + rc;
    const int bg = bb * NG + c / CPG;
    float s = 0.f, q = 0.f;
#pragma unroll
    for (int j = 0; j < 16; ++j) {
        s += partial[(bg * 16 + j) * 2];
        q += partial[(bg * 16 + j) * 2 + 1];
    }
    const float cnt = (float)(CPG * NSP);
    float mean = s / cnt;
    float var  = q / cnt - mean * mean;
    float rstd = rsqrtf(var + 1e-5f);
    float wf = w[c] * rstd, bv = b[c] - mean * wf;
    const float* px = x + ((size_t)bb * CH + c) * NSP + n0 + g * 16;
#pragma unroll
    for (int i = 0; i < 4; ++i) {
        float4 v = *(const float4*)(px + i * 4);
        T[g * 16 + i * 4 + 0][rc] = f2bf(v.x * wf + bv);
        T[g * 16 + i * 4 + 1][rc] = f2bf(v.y * wf + bv);
        T[g * 16 + i * 4 + 2][rc] = f2bf(v.z * wf + bv);
        T[g * 16 + i * 4 + 3][rc] = f2bf(v.w * wf + bv);
    }
    __syncthreads();
    int n = t >> 2, ch = (t & 3) * 16;
    uint4 o0 = *(const uint4*)&T[n][ch];
    uint4 o1 = *(const uint4*)&T[n][ch + 8];
    u16* dst = xnT + ((size_t)bb * NSP + n0 + n) * CH + c0 + ch;
    *(uint4*)dst = o0;
    *(uint4*)(dst + 8) = o1;
}

// ------- MFMA GEMM for QKV: Y[m][n] = sum_c Aw[m][c] * xnT[n][c] + bias[m] -------
__global__ __launch_bounds__(256) void gemm_qkv(const u16* __restrict__ Aw,
                                                const float* __restrict__ bias,
                                                const u16* __restrict__ xnT,
                                                u16* __restrict__ qT,
                                                u16* __restrict__ kT,
                                                u16* __restrict__ v) {
    const int n0 = blockIdx.x * 64, m0 = blockIdx.y * 64, bb = blockIdx.z;
    const int wave = threadIdx.x >> 6, lane = threadIdx.x & 63;
    const int lq = lane & 15, quad = lane >> 4;
    const int wm = (wave >> 1) * 32, wn = (wave & 1) * 32;
    f32x4 acc[2][2] = {};
    const u16* ap = Aw + (size_t)(m0 + wm + lq) * CH + quad * 8;
    const u16* bp = xnT + ((size_t)bb * NSP + n0 + wn + lq) * CH + quad * 8;
#pragma unroll
    for (int k0 = 0; k0 < CH; k0 += 32) {
        bf16x8 a0 = *(const bf16x8*)(ap + k0);
        bf16x8 a1 = *(const bf16x8*)(ap + 16 * CH + k0);
        bf16x8 b0 = *(const bf16x8*)(bp + k0);
        bf16x8 b1 = *(const bf16x8*)(bp + 16 * CH + k0);
        acc[0][0] = MFMA(a0, b0, acc[0][0], 0, 0, 0);
        acc[0][1] = MFMA(a0, b1, acc[0][1], 0, 0, 0);
        acc[1][0] = MFMA(a1, b0, acc[1][0], 0, 0, 0);
        acc[1][1] = MFMA(a1, b1, acc[1][1], 0, 0, 0);
    }
    const int sect = m0 >> 8;              // 0=Q, 1=K, 2=V
    const int h = (m0 & 255) >> 6;         // head for Q/K sections
#pragma unroll
    for (int im = 0; im < 2; ++im) {
        int ml = wm + im * 16 + quad * 4;  // +r, local m in [0,64)
        float4 bs = *(const float4*)(bias + m0 + ml);
#pragma unroll
        for (int in = 0; in < 2; ++in) {
            int n = n0 + wn + in * 16 + lq;
            f32x4 a = acc[im][in];
            float v0 = a[0] + bs.x, v1 = a[1] + bs.y;
            float v2 = a[2] + bs.z, v3 = a[3] + bs.w;
            if (sect < 2) {
                u16* base = (sect ? kT : qT) +
                            (((size_t)bb * NHD + h) * NSP + n) * HDIM + ml;
                ushort4 o;
                o.x = f2bf(v0); o.y = f2bf(v1); o.z = f2bf(v2); o.w = f2bf(v3);
                *(ushort4*)base = o;
            } else {
                u16* vb = v + ((size_t)bb * CH + (m0 - 512) + ml) * NSP + n;
                vb[0]        = f2bf(v0);
                vb[NSP]      = f2bf(v1);
                vb[2 * NSP]  = f2bf(v2);
                vb[3 * NSP]  = f2bf(v3);
            }
        }
    }
}

// ---------------- split-K, 2-q-tile MFMA flash attention ----------------
// Block = 64 queries, 4 waves: 2 q-groups (32 q each, 2 q-tiles/wave) x 2
// key-halves (2048 keys each, 32 iters of 64). Every Ks/Vs fragment read
// feeds TWO MFMAs (one per q-tile) -> half the LDS traffic per score of
// attn5; per-iter overhead amortized over 2x work; 2 independent MFMA
// chains/wave for ILP. 2-way (m,l,O) merge at the end via LDS.
__global__ __launch_bounds__(256, 2) void attn6(const u16* __restrict__ qT,
                                                const u16* __restrict__ kT,
                                                const u16* __restrict__ vN,
                                                u16* __restrict__ aoT) {
    __shared__ u16 Ks[2][64][72];                 // [khalf][key][ch]
    __shared__ u16 Vs[2][64][72];                 // [khalf][ch][key]
    __shared__ __align__(16) u16 Ps[4][32][72];   // per-wave P (aliased at merge)
    __shared__ float Ml[4][2][16][2];             // [wave][qt][lq][m,l]
    float (*Obuf)[32][68] = reinterpret_cast<float(*)[32][68]>(&Ps[0][0][0]);

    const int h = blockIdx.y, bb = blockIdx.z;
    const int t = threadIdx.x;
    const int wave = t >> 6, lane = t & 63;
    const int qg = wave >> 1, kh = wave & 1;
    const int lq = lane & 15, quad = lane >> 4;
    const int q_lo = blockIdx.x * 64 + qg * 32;

    // Q fragments for this wave's two q-tiles
    const u16* qpb = qT + (((size_t)bb * NHD + h) * NSP + q_lo + lq) * HDIM + quad * 8;
    bf16x8 qf[2][2];
    qf[0][0] = *(const bf16x8*)qpb;
    qf[0][1] = *(const bf16x8*)(qpb + 32);
    qf[1][0] = *(const bf16x8*)(qpb + 16 * HDIM);
    qf[1][1] = *(const bf16x8*)(qpb + 16 * HDIM + 32);

    const u16* kstage = kT + ((size_t)bb * NHD + h) * NSP * (size_t)HDIM;
    const u16* vstage = vN + ((size_t)bb * CH + h * HDIM) * NSP;
    const int srow = t >> 2, scol = (t & 3) * 8;

    // preload tile 0 of both key-halves
    uint4 pk[2][2], pv[2][2];
#pragma unroll
    for (int hh = 0; hh < 2; ++hh) {
        pk[hh][0] = *(const uint4*)(kstage + (size_t)(hh * 2048 + srow) * HDIM + scol);
        pk[hh][1] = *(const uint4*)(kstage + (size_t)(hh * 2048 + srow) * HDIM + scol + 32);
        pv[hh][0] = *(const uint4*)(vstage + (size_t)srow * NSP + hh * 2048 + scol);
        pv[hh][1] = *(const uint4*)(vstage + (size_t)srow * NSP + hh * 2048 + scol + 32);
    }

    float m[2] = {-1e30f, -1e30f}, l[2] = {0.f, 0.f};
    f32x4 O[2][4] = {};
    for (int kt = 0; kt < 32; ++kt) {
        __syncthreads();                 // prev iter's LDS reads complete
#pragma unroll
        for (int hh = 0; hh < 2; ++hh) {
            *(uint4*)&Ks[hh][srow][scol]      = pk[hh][0];
            *(uint4*)&Ks[hh][srow][scol + 32] = pk[hh][1];
            *(uint4*)&Vs[hh][srow][scol]      = pv[hh][0];
            *(uint4*)&Vs[hh][srow][scol + 32] = pv[hh][1];
        }
        __syncthreads();
        if (kt < 31) {                   // prefetch next tile during compute
            const int k1 = (kt + 1) * 64;
#pragma unroll
            for (int hh = 0; hh < 2; ++hh) {
                pk[hh][0] = *(const uint4*)(kstage + (size_t)(hh * 2048 + k1 + srow) * HDIM + scol);
                pk[hh][1] = *(const uint4*)(kstage + (size_t)(hh * 2048 + k1 + srow) * HDIM + scol + 32);
                pv[hh][0] = *(const uint4*)(vstage + (size_t)srow * NSP + hh * 2048 + k1 + scol);
                pv[hh][1] = *(const uint4*)(vstage + (size_t)srow * NSP + hh * 2048 + k1 + scol + 32);
            }
        }
        // S^T[key][q] for both q-tiles; each Ks frag feeds 2 MFMAs
        f32x4 st[2][4];
#pragma unroll
        for (int mt = 0; mt < 4; ++mt) {
            bf16x8 a0 = *(const bf16x8*)&Ks[kh][mt * 16 + lq][quad * 8];
            bf16x8 a1 = *(const bf16x8*)&Ks[kh][mt * 16 + lq][32 + quad * 8];
#pragma unroll
            for (int qt = 0; qt < 2; ++qt) {
                f32x4 acc = {0.f, 0.f, 0.f, 0.f};
                acc = MFMA(a0, qf[qt][0], acc, 0, 0, 0);
                acc = MFMA(a1, qf[qt][1], acc, 0, 0, 0);
                st[qt][mt] = acc * 0.125f;    // scale = hd^-0.5
            }
        }
        // online softmax per q-tile
        float alph[2];
#pragma unroll
        for (int qt = 0; qt < 2; ++qt) {
            float mx = m[qt];
#pragma unroll
            for (int mt = 0; mt < 4; ++mt)
#pragma unroll
                for (int r = 0; r < 4; ++r) mx = fmaxf(mx, st[qt][mt][r]);
            mx = fmaxf(mx, __shfl_xor(mx, 16));
            mx = fmaxf(mx, __shfl_xor(mx, 32));
            float alpha = __expf(m[qt] - mx);
            m[qt] = mx;
            float sum = 0.f;
#pragma unroll
            for (int mt = 0; mt < 4; ++mt) {
                float p0 = __expf(st[qt][mt][0] - mx);
                float p1 = __expf(st[qt][mt][1] - mx);
                float p2 = __expf(st[qt][mt][2] - mx);
                float p3 = __expf(st[qt][mt][3] - mx);
                sum += p0 + p1 + p2 + p3;
                ushort4 pkk;
                pkk.x = f2bf(p0); pkk.y = f2bf(p1); pkk.z = f2bf(p2); pkk.w = f2bf(p3);
                *(ushort4*)&Ps[wave][qt * 16 + lq][mt * 16 + quad * 4] = pkk;
            }
            sum += __shfl_xor(sum, 16);
            sum += __shfl_xor(sum, 32);
            l[qt] = l[qt] * alpha + sum;
            alph[qt] = alpha;
        }
        // PV: each Vs frag feeds 2 MFMAs
        bf16x8 pf[2][2];
        pf[0][0] = *(const bf16x8*)&Ps[wave][lq][quad * 8];
        pf[0][1] = *(const bf16x8*)&Ps[wave][lq][32 + quad * 8];
        pf[1][0] = *(const bf16x8*)&Ps[wave][16 + lq][quad * 8];
        pf[1][1] = *(const bf16x8*)&Ps[wave][16 + lq][32 + quad * 8];
#pragma unroll
        for (int mtc = 0; mtc < 4; ++mtc) {
            bf16x8 v0 = *(const bf16x8*)&Vs[kh][mtc * 16 + lq][quad * 8];
            bf16x8 v1 = *(const bf16x8*)&Vs[kh][mtc * 16 + lq][32 + quad * 8];
#pragma unroll
            for (int qt = 0; qt < 2; ++qt) {
                O[qt][mtc] *= alph[qt];
                O[qt][mtc] = MFMA(v0, pf[qt][0], O[qt][mtc], 0, 0, 0);
                O[qt][mtc] = MFMA(v1, pf[qt][1], O[qt][mtc], 0, 0, 0);
            }
        }
    }
    // ---- 2-way key-half merge ----
    if (lane < 16) {
        Ml[wave][0][lane][0] = m[0]; Ml[wave][0][lane][1] = l[0];
        Ml[wave][1][lane][0] = m[1]; Ml[wave][1][lane][1] = l[1];
    }
    __syncthreads();   // Ml visible; all Ps reads done -> Obuf alias safe
    const int w0 = qg * 2, w1 = qg * 2 + 1;
    float gl[2], aw[2];
#pragma unroll
    for (int qt = 0; qt < 2; ++qt) {
        float m0 = Ml[w0][qt][lq][0], l0 = Ml[w0][qt][lq][1];
        float m1 = Ml[w1][qt][lq][0], l1 = Ml[w1][qt][lq][1];
        float gm = fmaxf(m0, m1);
        gl[qt] = l0 * __expf(m0 - gm) + l1 * __expf(m1 - gm);
        aw[qt] = __expf(m[qt] - gm);
    }
    if (kh == 1) {
#pragma unroll
        for (int qt = 0; qt < 2; ++qt)
#pragma unroll
            for (int mtc = 0; mtc < 4; ++mtc)
                *(f32x4*)&Obuf[qg][qt * 16 + lq][mtc * 16 + quad * 4] = O[qt][mtc] * aw[qt];
    }
    __syncthreads();
    if (kh == 0) {
#pragma unroll
        for (int qt = 0; qt < 2; ++qt) {
            float linv = 1.f / gl[qt];
            u16* op = aoT + ((size_t)bb * NSP + q_lo + qt * 16 + lq) * CH + h * HDIM;
#pragma unroll
            for (int mtc = 0; mtc < 4; ++mtc) {
                f32x4 sres = O[qt][mtc] * aw[qt] +
                             *(const f32x4*)&Obuf[qg][qt * 16 + lq][mtc * 16 + quad * 4];
                ushort4 o;
                o.x = f2bf(sres[0] * linv);
                o.y = f2bf(sres[1] * linv);
                o.z = f2bf(sres[2] * linv);
                o.w = f2bf(sres[3] * linv);
                *(ushort4*)(op + mtc * 16 + quad * 4) = o;
            }
        }
    }
}

// ------- MFMA GEMM proj: out[b][m][n] = sum_c Pw[m][c]*aoT[n][c] + bias + x -------
__global__ __launch_bounds__(256) void gemm_proj(const u16* __restrict__ Aw,
                                                 const float* __restrict__ bias,
                                                 const u16* __restrict__ aoT,
                                                 const float* __restrict__ xres,
                                                 float* __restrict__ out) {
    const int n0 = blockIdx.x * 64, m0 = blockIdx.y * 64, bb = blockIdx.z;
    const int wave = threadIdx.x >> 6, lane = threadIdx.x & 63;
    const int lq = lane & 15, quad = lane >> 4;
    const int wm = (wave >> 1) * 32, wn = (wave & 1) * 32;
    f32x4 acc[2][2] = {};
    const u16* ap = Aw + (size_t)(m0 + wm + lq) * CH + quad * 8;
    const u16* bp = aoT + ((size_t)bb * NSP + n0 + wn + lq) * CH + quad * 8;
#pragma unroll
    for (int k0 = 0; k0 < CH; k0 += 32) {
        bf16x8 a0 = *(const bf16x8*)(ap + k0);
        bf16x8 a1 = *(const bf16x8*)(ap + 16 * CH + k0);
        bf16x8 b0 = *(const bf16x8*)(bp + k0);
        bf16x8 b1 = *(const bf16x8*)(bp + 16 * CH + k0);
        acc[0][0] = MFMA(a0, b0, acc[0][0], 0, 0, 0);
        acc[0][1] = MFMA(a0, b1, acc[0][1], 0, 0, 0);
        acc[1][0] = MFMA(a1, b0, acc[1][0], 0, 0, 0);
        acc[1][1] = MFMA(a1, b1, acc[1][1], 0, 0, 0);
    }
#pragma unroll
    for (int im = 0; im < 2; ++im) {
        int ml = wm + im * 16 + quad * 4;
        float4 bs = *(const float4*)(bias + m0 + ml);
        float bsv[4] = {bs.x, bs.y, bs.z, bs.w};
#pragma unroll
        for (int in = 0; in < 2; ++in) {
            int n = n0 + wn + in * 16 + lq;
            f32x4 a = acc[im][in];
#pragma unroll
            for (int r = 0; r < 4; ++r) {
                size_t idx = ((size_t)bb * CH + m0 + ml + r) * NSP + n;
                out[idx] = a[r] + bsv[r] + xres[idx];
            }
        }
    }
}

extern "C" void kernel_launch(void* const* d_in, const int* in_sizes, int n_in,
                              void* d_out, int out_size, void* d_ws, size_t ws_size,
                              hipStream_t stream) {
    const float* x      = (const float*)d_in[0];
    const float* norm_w = (const float*)d_in[1];
    const float* norm_b = (const float*)d_in[2];
    const float* qkv_w  = (const float*)d_in[3];
    const float* qkv_b  = (const float*)d_in[4];
    const float* proj_w = (const float*)d_in[5];
    const float* proj_b = (const float*)d_in[6];
    float* out = (float*)d_out;

    char* w = (char*)d_ws;
    float* partial = (float*)w;                       // 4 KB (16x16x2 fp32)
    u16* wqb = (u16*)(w + 4096);                      // 384 KB (768x256 bf16)
    u16* wpb = (u16*)(w + 4096 + 393216);             // 128 KB (256x256 bf16)
    u16* xnT = (u16*)(w + 528384);                    // 4 MB [b][n][c] (aliased by aoT)
    u16* qT  = (u16*)(w + 528384 + 4194304);          // 4 MB [b][h][n][c]
    u16* kT  = (u16*)(w + 528384 + 2 * 4194304);      // 4 MB [b][h][n][c]
    u16* v   = (u16*)(w + 528384 + 3 * 4194304);      // 4 MB [b][c][n]
    u16* aoT = xnT;                                   // xnT dead after gemm_qkv

    wconv2<<<dim3(256), 256, 0, stream>>>(qkv_w, proj_w, wqb, wpb);
    gn_part<<<dim3(NB * NG, 16), 256, 0, stream>>>(x, partial);
    gn_apply_t<<<dim3(NSP / 64, CH / 64, NB), 256, 0, stream>>>(
        x, partial, norm_w, norm_b, xnT);
    gemm_qkv<<<dim3(NSP / 64, (3 * CH) / 64, NB), 256, 0, stream>>>(
        wqb, qkv_b, xnT, qT, kT, v);
    attn6<<<dim3(NSP / 64, NHD, NB), 256, 0, stream>>>(qT, kT, v, aoT);
    gemm_proj<<<dim3(NSP / 64, CH / 64, NB), 256, 0, stream>>>(
        wpb, proj_b, aoT, x, out);
}

// Round 9
// 185.230 us; speedup vs baseline: 1.3064x; 1.3064x over previous
//
#include <hip/hip_runtime.h>
#include <hip/hip_bf16.h>

#define NSP 4096      // D*H*W
#define CH 256
#define NB 2
#define NG 8
#define CPG 32        // channels per group
#define NHD 4         // heads
#define HDIM 64       // head dim

typedef unsigned short u16;
typedef unsigned int u32;
typedef __attribute__((ext_vector_type(8))) short bf16x8;
typedef __attribute__((ext_vector_type(4))) float f32x4;

#define MFMA __builtin_amdgcn_mfma_f32_16x16x32_bf16

__device__ __forceinline__ u16 f2bf(float f) {
    u32 i = __float_as_uint(f);
    u32 r = (i + 0x7FFFu + ((i >> 16) & 1u)) >> 16;   // round-nearest-even
    return (u16)r;
}

// async global->LDS DMA: wave loads 1 KB (16 B/lane); lds dst = uniform base + lane*16
__device__ __forceinline__ void dma16(const u16* g, u16* l) {
    __builtin_amdgcn_global_load_lds(
        (const __attribute__((address_space(1))) void*)g,
        (__attribute__((address_space(3))) void*)l, 16, 0, 0);
}

// ---------------- fp32 -> bf16 weight conversion (qkv_w ++ proj_w) ----------------
__global__ __launch_bounds__(256) void wconv2(const float* __restrict__ qw,
                                              const float* __restrict__ pw,
                                              u16* __restrict__ wqb,
                                              u16* __restrict__ wpb) {
    int i = (blockIdx.x * 256 + threadIdx.x) * 4;
    const float* src; u16* dst;
    if (i < 3 * CH * CH) { src = qw + i; dst = wqb + i; }
    else { src = pw + (i - 3 * CH * CH); dst = wpb + (i - 3 * CH * CH); }
    float4 v = *(const float4*)src;
    ushort4 o;
    o.x = f2bf(v.x); o.y = f2bf(v.y); o.z = f2bf(v.z); o.w = f2bf(v.w);
    *(ushort4*)dst = o;
}

// ---------------- GroupNorm partial stats: grid (16 bg, 16 chunks) ----------------
__global__ __launch_bounds__(256) void gn_part(const float* __restrict__ x,
                                               float* __restrict__ partial) {
    const int bg = blockIdx.x, chunk = blockIdx.y;
    const float* p = x + (size_t)bg * (CPG * NSP) + chunk * 8192;
    float s = 0.f, ss = 0.f;
    for (int i = threadIdx.x; i < 2048; i += 256) {   // 8192 floats
        float4 u = ((const float4*)p)[i];
        s += u.x + u.y + u.z + u.w;
        ss += u.x * u.x + u.y * u.y + u.z * u.z + u.w * u.w;
    }
    for (int off = 32; off > 0; off >>= 1) {
        s += __shfl_down(s, off);
        ss += __shfl_down(ss, off);
    }
    __shared__ float red[4][2];
    const int wv = threadIdx.x >> 6;
    if ((threadIdx.x & 63) == 0) { red[wv][0] = s; red[wv][1] = ss; }
    __syncthreads();
    if (threadIdx.x == 0) {
        float ts = red[0][0] + red[1][0] + red[2][0] + red[3][0];
        float tq = red[0][1] + red[1][1] + red[2][1] + red[3][1];
        partial[(bg * 16 + chunk) * 2]     = ts;
        partial[(bg * 16 + chunk) * 2 + 1] = tq;
    }
}

// ------- GroupNorm apply + transpose: x[b][c][n] fp32 -> xnT[b][n][c] bf16 -------
__global__ __launch_bounds__(256) void gn_apply_t(const float* __restrict__ x,
                                                  const float* __restrict__ partial,
                                                  const float* __restrict__ w,
                                                  const float* __restrict__ b,
                                                  u16* __restrict__ xnT) {
    __shared__ u16 T[64][72];   // [n][c], pitch 144 B
    const int n0 = blockIdx.x * 64, c0 = blockIdx.y * 64, bb = blockIdx.z;
    const int t = threadIdx.x;
    const int rc = t & 63;          // channel within tile
    const int g  = t >> 6;          // n-chunk group of 16
    const int c  = c0 + rc;
    const int bg = bb * NG + c / CPG;
    float s = 0.f, q = 0.f;
#pragma unroll
    for (int j = 0; j < 16; ++j) {
        s += partial[(bg * 16 + j) * 2];
        q += partial[(bg * 16 + j) * 2 + 1];
    }
    const float cnt = (float)(CPG * NSP);
    float mean = s / cnt;
    float var  = q / cnt - mean * mean;
    float rstd = rsqrtf(var + 1e-5f);
    float wf = w[c] * rstd, bv = b[c] - mean * wf;
    const float* px = x + ((size_t)bb * CH + c) * NSP + n0 + g * 16;
#pragma unroll
    for (int i = 0; i < 4; ++i) {
        float4 v = *(const float4*)(px + i * 4);
        T[g * 16 + i * 4 + 0][rc] = f2bf(v.x * wf + bv);
        T[g * 16 + i * 4 + 1][rc] = f2bf(v.y * wf + bv);
        T[g * 16 + i * 4 + 2][rc] = f2bf(v.z * wf + bv);
        T[g * 16 + i * 4 + 3][rc] = f2bf(v.w * wf + bv);
    }
    __syncthreads();
    int n = t >> 2, ch = (t & 3) * 16;
    uint4 o0 = *(const uint4*)&T[n][ch];
    uint4 o1 = *(const uint4*)&T[n][ch + 8];
    u16* dst = xnT + ((size_t)bb * NSP + n0 + n) * CH + c0 + ch;
    *(uint4*)dst = o0;
    *(uint4*)(dst + 8) = o1;
}

// ------- MFMA GEMM for QKV: Y[m][n] = sum_c Aw[m][c] * xnT[n][c] + bias[m] -------
// Epilogue writes qT/kT [b][h][n][64] with XOR chunk swizzle (chunk c of row n
// stored at c^(n&7)), and V [b][c][n] with the same swizzle applied within each
// aligned 64-key (128 B) block keyed by (c&7) -- enables conflict-minimal LDS
// images via linear global_load_lds DMA in attn7.
__global__ __launch_bounds__(256) void gemm_qkv(const u16* __restrict__ Aw,
                                                const float* __restrict__ bias,
                                                const u16* __restrict__ xnT,
                                                u16* __restrict__ qT,
                                                u16* __restrict__ kT,
                                                u16* __restrict__ v) {
    const int n0 = blockIdx.x * 64, m0 = blockIdx.y * 64, bb = blockIdx.z;
    const int wave = threadIdx.x >> 6, lane = threadIdx.x & 63;
    const int lq = lane & 15, quad = lane >> 4;
    const int wm = (wave >> 1) * 32, wn = (wave & 1) * 32;
    f32x4 acc[2][2] = {};
    const u16* ap = Aw + (size_t)(m0 + wm + lq) * CH + quad * 8;
    const u16* bp = xnT + ((size_t)bb * NSP + n0 + wn + lq) * CH + quad * 8;
#pragma unroll
    for (int k0 = 0; k0 < CH; k0 += 32) {
        bf16x8 a0 = *(const bf16x8*)(ap + k0);
        bf16x8 a1 = *(const bf16x8*)(ap + 16 * CH + k0);
        bf16x8 b0 = *(const bf16x8*)(bp + k0);
        bf16x8 b1 = *(const bf16x8*)(bp + 16 * CH + k0);
        acc[0][0] = MFMA(a0, b0, acc[0][0], 0, 0, 0);
        acc[0][1] = MFMA(a0, b1, acc[0][1], 0, 0, 0);
        acc[1][0] = MFMA(a1, b0, acc[1][0], 0, 0, 0);
        acc[1][1] = MFMA(a1, b1, acc[1][1], 0, 0, 0);
    }
    const int sect = m0 >> 8;              // 0=Q, 1=K, 2=V
    const int h = (m0 & 255) >> 6;         // head for Q/K sections
#pragma unroll
    for (int im = 0; im < 2; ++im) {
        int ml = wm + im * 16 + quad * 4;  // +r, local m in [0,64)
        float4 bs = *(const float4*)(bias + m0 + ml);
#pragma unroll
        for (int in = 0; in < 2; ++in) {
            int n = n0 + wn + in * 16 + lq;
            f32x4 a = acc[im][in];
            float v0 = a[0] + bs.x, v1 = a[1] + bs.y;
            float v2 = a[2] + bs.z, v3 = a[3] + bs.w;
            if (sect < 2) {
                int lc = ml >> 3, sub = ml & 7;
                int colp = ((lc ^ (n & 7)) << 3) | sub;   // XOR chunk swizzle
                u16* base = (sect ? kT : qT) +
                            (((size_t)bb * NHD + h) * NSP + n) * HDIM + colp;
                ushort4 o;
                o.x = f2bf(v0); o.y = f2bf(v1); o.z = f2bf(v2); o.w = f2bf(v3);
                *(ushort4*)base = o;
            } else {
                float vv[4] = {v0, v1, v2, v3};
#pragma unroll
                for (int r = 0; r < 4; ++r) {
                    int ch = (m0 - 512) + ml + r;
                    // swizzle within the aligned 64-key block, keyed by ch&7
                    int pos = (n & ~63) + ((((n >> 3) & 7) ^ (ch & 7)) << 3) + (n & 7);
                    v[((size_t)bb * CH + ch) * NSP + pos] = f2bf(vv[r]);
                }
            }
        }
    }
}

// ---------------- attn7: split-K flash attention, DMA-staged swizzled LDS ----
// 512 thr = 8 waves = 4 q-groups (32 q) x 2 key-halves (2048 keys, 32 iters).
// K/V tiles DMA'd (global_load_lds 16B) into double-buffered swizzled LDS,
// one __syncthreads per iter (vmcnt(0) drain before barrier completes DMA).
// Each fragment read feeds 2 MFMAs. 2-way (m,l,O) merge, partner = wave^4.
__global__ __launch_bounds__(512, 2) void attn7(const u16* __restrict__ qT,
                                                const u16* __restrict__ kT,
                                                const u16* __restrict__ vN,
                                                u16* __restrict__ aoT) {
    __shared__ u16 Ks[2][2][64][64];   // [khalf][buf][key][ch-swizzled]  32 KB
    __shared__ u16 Vs[2][2][64][64];   // [khalf][buf][ch][key-swizzled]  32 KB
    __shared__ __align__(16) char smem_ps[8 * 32 * 72 * 2];   // Ps / Obuf alias
    __shared__ float Ml[8][2][16][2];
    u16 (*Ps)[32][72] = reinterpret_cast<u16(*)[32][72]>(smem_ps);
    float (*Obuf)[32][68] = reinterpret_cast<float(*)[32][68]>(smem_ps);

    const int h = blockIdx.y, bb = blockIdx.z;
    const int t = threadIdx.x;
    const int wave = t >> 6, lane = t & 63;
    const int qg = wave & 3, kh = wave >> 2;
    const int lq = lane & 15, quad = lane >> 4;
    const int q_lo = blockIdx.x * 128 + qg * 32;

    // Q fragments (swizzled global layout), two q-tiles
    const int pr = quad ^ (lq & 7);
    const u16* qrow0 = qT + (((size_t)bb * NHD + h) * NSP + q_lo + lq) * HDIM;
    bf16x8 qf[2][2];
    qf[0][0] = *(const bf16x8*)(qrow0 + pr * 8);
    qf[0][1] = *(const bf16x8*)(qrow0 + (pr ^ 4) * 8);
    qf[1][0] = *(const bf16x8*)(qrow0 + 16 * HDIM + pr * 8);
    qf[1][1] = *(const bf16x8*)(qrow0 + 16 * HDIM + (pr ^ 4) * 8);

    const u16* khead = kT + ((size_t)bb * NHD + h) * NSP * (size_t)HDIM;
    const u16* vhead = vN + ((size_t)bb * CH + h * HDIM) * NSP;

    // per-wave staging role: waves 0-3 stage K (kh_s = wave>>1), 4-7 stage V
    const int sK   = (wave < 4);
    const int kh_s = (wave >> 1) & 1;
    const int rbase = (wave & 1) * 32;
    // prologue: DMA tile 0 into buf 0
    {
#pragma unroll
        for (int j = 0; j < 4; ++j) {
            int r8 = rbase + j * 8;
            if (sK) {
                dma16(khead + (size_t)(kh_s * 2048 + r8) * HDIM + lane * 8,
                      &Ks[kh_s][0][r8][0]);
            } else {
                dma16(vhead + (size_t)(r8 + (lane >> 3)) * NSP + kh_s * 2048 + (lane & 7) * 8,
                      &Vs[kh_s][0][r8][0]);
            }
        }
    }

    float m[2] = {-1e30f, -1e30f}, l[2] = {0.f, 0.f};
    f32x4 O[2][4] = {};
    for (int kt = 0; kt < 32; ++kt) {
        const int cur = kt & 1;
        __syncthreads();   // drains this wave's DMA (vmcnt 0) + syncs buffers
        if (kt < 31) {     // DMA tile kt+1 into buf cur^1, overlaps compute
            const int K1 = (kt + 1) * 64;
#pragma unroll
            for (int j = 0; j < 4; ++j) {
                int r8 = rbase + j * 8;
                if (sK) {
                    dma16(khead + (size_t)(kh_s * 2048 + K1 + r8) * HDIM + lane * 8,
                          &Ks[kh_s][cur ^ 1][r8][0]);
                } else {
                    dma16(vhead + (size_t)(r8 + (lane >> 3)) * NSP + kh_s * 2048 + K1 + (lane & 7) * 8,
                          &Vs[kh_s][cur ^ 1][r8][0]);
                }
            }
        }
        // S^T[key][q] for both q-tiles; each Ks frag feeds 2 MFMAs
        f32x4 st[2][4];
#pragma unroll
        for (int mt = 0; mt < 4; ++mt) {
            bf16x8 a0 = *(const bf16x8*)&Ks[kh][cur][mt * 16 + lq][pr * 8];
            bf16x8 a1 = *(const bf16x8*)&Ks[kh][cur][mt * 16 + lq][(pr ^ 4) * 8];
#pragma unroll
            for (int qt = 0; qt < 2; ++qt) {
                f32x4 acc = {0.f, 0.f, 0.f, 0.f};
                acc = MFMA(a0, qf[qt][0], acc, 0, 0, 0);
                acc = MFMA(a1, qf[qt][1], acc, 0, 0, 0);
                st[qt][mt] = acc * 0.125f;    // scale = hd^-0.5
            }
        }
        // online softmax per q-tile (lane's 16 scores all on one query)
        float alph[2];
#pragma unroll
        for (int qt = 0; qt < 2; ++qt) {
            float mx = m[qt];
#pragma unroll
            for (int mt = 0; mt < 4; ++mt)
#pragma unroll
                for (int r = 0; r < 4; ++r) mx = fmaxf(mx, st[qt][mt][r]);
            mx = fmaxf(mx, __shfl_xor(mx, 16));
            mx = fmaxf(mx, __shfl_xor(mx, 32));
            float alpha = __expf(m[qt] - mx);
            m[qt] = mx;
            float sum = 0.f;
#pragma unroll
            for (int mt = 0; mt < 4; ++mt) {
                float p0 = __expf(st[qt][mt][0] - mx);
                float p1 = __expf(st[qt][mt][1] - mx);
                float p2 = __expf(st[qt][mt][2] - mx);
                float p3 = __expf(st[qt][mt][3] - mx);
                sum += p0 + p1 + p2 + p3;
                ushort4 pkk;
                pkk.x = f2bf(p0); pkk.y = f2bf(p1); pkk.z = f2bf(p2); pkk.w = f2bf(p3);
                *(ushort4*)&Ps[wave][qt * 16 + lq][mt * 16 + quad * 4] = pkk;
            }
            sum += __shfl_xor(sum, 16);
            sum += __shfl_xor(sum, 32);
            l[qt] = l[qt] * alpha + sum;
            alph[qt] = alpha;
        }
        // PV: each Vs frag feeds 2 MFMAs
        bf16x8 pf[2][2];
        pf[0][0] = *(const bf16x8*)&Ps[wave][lq][quad * 8];
        pf[0][1] = *(const bf16x8*)&Ps[wave][lq][32 + quad * 8];
        pf[1][0] = *(const bf16x8*)&Ps[wave][16 + lq][quad * 8];
        pf[1][1] = *(const bf16x8*)&Ps[wave][16 + lq][32 + quad * 8];
#pragma unroll
        for (int mtc = 0; mtc < 4; ++mtc) {
            bf16x8 v0 = *(const bf16x8*)&Vs[kh][cur][mtc * 16 + lq][pr * 8];
            bf16x8 v1 = *(const bf16x8*)&Vs[kh][cur][mtc * 16 + lq][(pr ^ 4) * 8];
#pragma unroll
            for (int qt = 0; qt < 2; ++qt) {
                O[qt][mtc] *= alph[qt];
                O[qt][mtc] = MFMA(v0, pf[qt][0], O[qt][mtc], 0, 0, 0);
                O[qt][mtc] = MFMA(v1, pf[qt][1], O[qt][mtc], 0, 0, 0);
            }
        }
    }
    // ---- 2-way key-half merge (partner = wave^4) ----
    if (lane < 16) {
        Ml[wave][0][lane][0] = m[0]; Ml[wave][0][lane][1] = l[0];
        Ml[wave][1][lane][0] = m[1]; Ml[wave][1][lane][1] = l[1];
    }
    __syncthreads();   // Ml visible; all Ps reads done -> Obuf alias safe
    float gl[2], aw[2];
#pragma unroll
    for (int qt = 0; qt < 2; ++qt) {
        float mA = Ml[qg][qt][lq][0],     lA = Ml[qg][qt][lq][1];
        float mB = Ml[qg + 4][qt][lq][0], lB = Ml[qg + 4][qt][lq][1];
        float gm = fmaxf(mA, mB);
        gl[qt] = lA * __expf(mA - gm) + lB * __expf(mB - gm);
        aw[qt] = __expf(m[qt] - gm);
    }
    if (kh == 1) {
#pragma unroll
        for (int qt = 0; qt < 2; ++qt)
#pragma unroll
            for (int mtc = 0; mtc < 4; ++mtc)
                *(f32x4*)&Obuf[qg][qt * 16 + lq][mtc * 16 + quad * 4] = O[qt][mtc] * aw[qt];
    }
    __syncthreads();
    if (kh == 0) {
#pragma unroll
        for (int qt = 0; qt < 2; ++qt) {
            float linv = 1.f / gl[qt];
            u16* op = aoT + ((size_t)bb * NSP + q_lo + qt * 16 + lq) * CH + h * HDIM;
#pragma unroll
            for (int mtc = 0; mtc < 4; ++mtc) {
                f32x4 sres = O[qt][mtc] * aw[qt] +
                             *(const f32x4*)&Obuf[qg][qt * 16 + lq][mtc * 16 + quad * 4];
                ushort4 o;
                o.x = f2bf(sres[0] * linv);
                o.y = f2bf(sres[1] * linv);
                o.z = f2bf(sres[2] * linv);
                o.w = f2bf(sres[3] * linv);
                *(ushort4*)(op + mtc * 16 + quad * 4) = o;
            }
        }
    }
}

// ------- MFMA GEMM proj: out[b][m][n] = sum_c Pw[m][c]*aoT[n][c] + bias + x -------
__global__ __launch_bounds__(256) void gemm_proj(const u16* __restrict__ Aw,
                                                 const float* __restrict__ bias,
                                                 const u16* __restrict__ aoT,
                                                 const float* __restrict__ xres,
                                                 float* __restrict__ out) {
    const int n0 = blockIdx.x * 64, m0 = blockIdx.y * 64, bb = blockIdx.z;
    const int wave = threadIdx.x >> 6, lane = threadIdx.x & 63;
    const int lq = lane & 15, quad = lane >> 4;
    const int wm = (wave >> 1) * 32, wn = (wave & 1) * 32;
    f32x4 acc[2][2] = {};
    const u16* ap = Aw + (size_t)(m0 + wm + lq) * CH + quad * 8;
    const u16* bp = aoT + ((size_t)bb * NSP + n0 + wn + lq) * CH + quad * 8;
#pragma unroll
    for (int k0 = 0; k0 < CH; k0 += 32) {
        bf16x8 a0 = *(const bf16x8*)(ap + k0);
        bf16x8 a1 = *(const bf16x8*)(ap + 16 * CH + k0);
        bf16x8 b0 = *(const bf16x8*)(bp + k0);
        bf16x8 b1 = *(const bf16x8*)(bp + 16 * CH + k0);
        acc[0][0] = MFMA(a0, b0, acc[0][0], 0, 0, 0);
        acc[0][1] = MFMA(a0, b1, acc[0][1], 0, 0, 0);
        acc[1][0] = MFMA(a1, b0, acc[1][0], 0, 0, 0);
        acc[1][1] = MFMA(a1, b1, acc[1][1], 0, 0, 0);
    }
#pragma unroll
    for (int im = 0; im < 2; ++im) {
        int ml = wm + im * 16 + quad * 4;
        float4 bs = *(const float4*)(bias + m0 + ml);
        float bsv[4] = {bs.x, bs.y, bs.z, bs.w};
#pragma unroll
        for (int in = 0; in < 2; ++in) {
            int n = n0 + wn + in * 16 + lq;
            f32x4 a = acc[im][in];
#pragma unroll
            for (int r = 0; r < 4; ++r) {
                size_t idx = ((size_t)bb * CH + m0 + ml + r) * NSP + n;
                out[idx] = a[r] + bsv[r] + xres[idx];
            }
        }
    }
}

extern "C" void kernel_launch(void* const* d_in, const int* in_sizes, int n_in,
                              void* d_out, int out_size, void* d_ws, size_t ws_size,
                              hipStream_t stream) {
    const float* x      = (const float*)d_in[0];
    const float* norm_w = (const float*)d_in[1];
    const float* norm_b = (const float*)d_in[2];
    const float* qkv_w  = (const float*)d_in[3];
    const float* qkv_b  = (const float*)d_in[4];
    const float* proj_w = (const float*)d_in[5];
    const float* proj_b = (const float*)d_in[6];
    float* out = (float*)d_out;

    char* w = (char*)d_ws;
    float* partial = (float*)w;                       // 4 KB (16x16x2 fp32)
    u16* wqb = (u16*)(w + 4096);                      // 384 KB (768x256 bf16)
    u16* wpb = (u16*)(w + 4096 + 393216);             // 128 KB (256x256 bf16)
    u16* xnT = (u16*)(w + 528384);                    // 4 MB [b][n][c] (aliased by aoT)
    u16* qT  = (u16*)(w + 528384 + 4194304);          // 4 MB [b][h][n][64] swizzled
    u16* kT  = (u16*)(w + 528384 + 2 * 4194304);      // 4 MB [b][h][n][64] swizzled
    u16* v   = (u16*)(w + 528384 + 3 * 4194304);      // 4 MB [b][c][n] swizzled blocks
    u16* aoT = xnT;                                   // xnT dead after gemm_qkv

    wconv2<<<dim3(256), 256, 0, stream>>>(qkv_w, proj_w, wqb, wpb);
    gn_part<<<dim3(NB * NG, 16), 256, 0, stream>>>(x, partial);
    gn_apply_t<<<dim3(NSP / 64, CH / 64, NB), 256, 0, stream>>>(
        x, partial, norm_w, norm_b, xnT);
    gemm_qkv<<<dim3(NSP / 64, (3 * CH) / 64, NB), 256, 0, stream>>>(
        wqb, qkv_b, xnT, qT, kT, v);
    attn7<<<dim3(NSP / 128, NHD, NB), 512, 0, stream>>>(qT, kT, v, aoT);
    gemm_proj<<<dim3(NSP / 64, CH / 64, NB), 256, 0, stream>>>(
        wpb, proj_b, aoT, x, out);
}

// Round 10
// 173.136 us; speedup vs baseline: 1.3976x; 1.0699x over previous
//
#include <hip/hip_runtime.h>
#include <hip/hip_bf16.h>

#define NSP 4096      // D*H*W
#define CH 256
#define NB 2
#define NG 8
#define CPG 32        // channels per group
#define NHD 4         // heads
#define HDIM 64       // head dim

typedef unsigned short u16;
typedef unsigned int u32;
typedef __attribute__((ext_vector_type(8))) short bf16x8;
typedef __attribute__((ext_vector_type(4))) float f32x4;

#define MFMA __builtin_amdgcn_mfma_f32_16x16x32_bf16
#define QSCALE 0.18033688f   // 0.125 * log2(e): folds attn scale + exp2 domain

__device__ __forceinline__ u16 f2bf(float f) {
    u32 i = __float_as_uint(f);
    u32 r = (i + 0x7FFFu + ((i >> 16) & 1u)) >> 16;   // round-nearest-even
    return (u16)r;
}

// async global->LDS DMA: wave loads 1 KB (16 B/lane); lds dst = uniform base + lane*16
__device__ __forceinline__ void dma16(const u16* g, u16* l) {
    __builtin_amdgcn_global_load_lds(
        (const __attribute__((address_space(1))) void*)g,
        (__attribute__((address_space(3))) void*)l, 16, 0, 0);
}

// ---------------- fp32 -> bf16 weight conversion (qkv_w ++ proj_w) ----------------
__global__ __launch_bounds__(256) void wconv2(const float* __restrict__ qw,
                                              const float* __restrict__ pw,
                                              u16* __restrict__ wqb,
                                              u16* __restrict__ wpb) {
    int i = (blockIdx.x * 256 + threadIdx.x) * 4;
    const float* src; u16* dst;
    if (i < 3 * CH * CH) { src = qw + i; dst = wqb + i; }
    else { src = pw + (i - 3 * CH * CH); dst = wpb + (i - 3 * CH * CH); }
    float4 v = *(const float4*)src;
    ushort4 o;
    o.x = f2bf(v.x); o.y = f2bf(v.y); o.z = f2bf(v.z); o.w = f2bf(v.w);
    *(ushort4*)dst = o;
}

// ---------------- GroupNorm partial stats: grid (16 bg, 16 chunks) ----------------
__global__ __launch_bounds__(256) void gn_part(const float* __restrict__ x,
                                               float* __restrict__ partial) {
    const int bg = blockIdx.x, chunk = blockIdx.y;
    const float* p = x + (size_t)bg * (CPG * NSP) + chunk * 8192;
    float s = 0.f, ss = 0.f;
    for (int i = threadIdx.x; i < 2048; i += 256) {   // 8192 floats
        float4 u = ((const float4*)p)[i];
        s += u.x + u.y + u.z + u.w;
        ss += u.x * u.x + u.y * u.y + u.z * u.z + u.w * u.w;
    }
    for (int off = 32; off > 0; off >>= 1) {
        s += __shfl_down(s, off);
        ss += __shfl_down(ss, off);
    }
    __shared__ float red[4][2];
    const int wv = threadIdx.x >> 6;
    if ((threadIdx.x & 63) == 0) { red[wv][0] = s; red[wv][1] = ss; }
    __syncthreads();
    if (threadIdx.x == 0) {
        float ts = red[0][0] + red[1][0] + red[2][0] + red[3][0];
        float tq = red[0][1] + red[1][1] + red[2][1] + red[3][1];
        partial[(bg * 16 + chunk) * 2]     = ts;
        partial[(bg * 16 + chunk) * 2 + 1] = tq;
    }
}

// ------- GroupNorm apply + transpose: x[b][c][n] fp32 -> xnT[b][n][c] bf16 -------
__global__ __launch_bounds__(256) void gn_apply_t(const float* __restrict__ x,
                                                  const float* __restrict__ partial,
                                                  const float* __restrict__ w,
                                                  const float* __restrict__ b,
                                                  u16* __restrict__ xnT) {
    __shared__ u16 T[64][72];   // [n][c], pitch 144 B
    const int n0 = blockIdx.x * 64, c0 = blockIdx.y * 64, bb = blockIdx.z;
    const int t = threadIdx.x;
    const int rc = t & 63;          // channel within tile
    const int g  = t >> 6;          // n-chunk group of 16
    const int c  = c0 + rc;
    const int bg = bb * NG + c / CPG;
    float s = 0.f, q = 0.f;
#pragma unroll
    for (int j = 0; j < 16; ++j) {
        s += partial[(bg * 16 + j) * 2];
        q += partial[(bg * 16 + j) * 2 + 1];
    }
    const float cnt = (float)(CPG * NSP);
    float mean = s / cnt;
    float var  = q / cnt - mean * mean;
    float rstd = rsqrtf(var + 1e-5f);
    float wf = w[c] * rstd, bv = b[c] - mean * wf;
    const float* px = x + ((size_t)bb * CH + c) * NSP + n0 + g * 16;
#pragma unroll
    for (int i = 0; i < 4; ++i) {
        float4 v = *(const float4*)(px + i * 4);
        T[g * 16 + i * 4 + 0][rc] = f2bf(v.x * wf + bv);
        T[g * 16 + i * 4 + 1][rc] = f2bf(v.y * wf + bv);
        T[g * 16 + i * 4 + 2][rc] = f2bf(v.z * wf + bv);
        T[g * 16 + i * 4 + 3][rc] = f2bf(v.w * wf + bv);
    }
    __syncthreads();
    int n = t >> 2, ch = (t & 3) * 16;
    uint4 o0 = *(const uint4*)&T[n][ch];
    uint4 o1 = *(const uint4*)&T[n][ch + 8];
    u16* dst = xnT + ((size_t)bb * NSP + n0 + n) * CH + c0 + ch;
    *(uint4*)dst = o0;
    *(uint4*)(dst + 8) = o1;
}

// ------- MFMA GEMM for QKV: Y[m][n] = sum_c Aw[m][c] * xnT[n][c] + bias[m] -------
// Epilogue: qT/kT [b][h][n][64] XOR-chunk-swizzled; V [b][c][n] block-swizzled.
// Q additionally pre-scaled by QSCALE (attn math moves to exp2 domain).
__global__ __launch_bounds__(256) void gemm_qkv(const u16* __restrict__ Aw,
                                                const float* __restrict__ bias,
                                                const u16* __restrict__ xnT,
                                                u16* __restrict__ qT,
                                                u16* __restrict__ kT,
                                                u16* __restrict__ v) {
    const int n0 = blockIdx.x * 64, m0 = blockIdx.y * 64, bb = blockIdx.z;
    const int wave = threadIdx.x >> 6, lane = threadIdx.x & 63;
    const int lq = lane & 15, quad = lane >> 4;
    const int wm = (wave >> 1) * 32, wn = (wave & 1) * 32;
    f32x4 acc[2][2] = {};
    const u16* ap = Aw + (size_t)(m0 + wm + lq) * CH + quad * 8;
    const u16* bp = xnT + ((size_t)bb * NSP + n0 + wn + lq) * CH + quad * 8;
#pragma unroll
    for (int k0 = 0; k0 < CH; k0 += 32) {
        bf16x8 a0 = *(const bf16x8*)(ap + k0);
        bf16x8 a1 = *(const bf16x8*)(ap + 16 * CH + k0);
        bf16x8 b0 = *(const bf16x8*)(bp + k0);
        bf16x8 b1 = *(const bf16x8*)(bp + 16 * CH + k0);
        acc[0][0] = MFMA(a0, b0, acc[0][0], 0, 0, 0);
        acc[0][1] = MFMA(a0, b1, acc[0][1], 0, 0, 0);
        acc[1][0] = MFMA(a1, b0, acc[1][0], 0, 0, 0);
        acc[1][1] = MFMA(a1, b1, acc[1][1], 0, 0, 0);
    }
    const int sect = m0 >> 8;              // 0=Q, 1=K, 2=V
    const int h = (m0 & 255) >> 6;         // head for Q/K sections
    const float osc = (sect == 0) ? QSCALE : 1.f;
#pragma unroll
    for (int im = 0; im < 2; ++im) {
        int ml = wm + im * 16 + quad * 4;  // +r, local m in [0,64)
        float4 bs = *(const float4*)(bias + m0 + ml);
#pragma unroll
        for (int in = 0; in < 2; ++in) {
            int n = n0 + wn + in * 16 + lq;
            f32x4 a = acc[im][in];
            float v0 = (a[0] + bs.x) * osc, v1 = (a[1] + bs.y) * osc;
            float v2 = (a[2] + bs.z) * osc, v3 = (a[3] + bs.w) * osc;
            if (sect < 2) {
                int lc = ml >> 3, sub = ml & 7;
                int colp = ((lc ^ (n & 7)) << 3) | sub;   // XOR chunk swizzle
                u16* base = (sect ? kT : qT) +
                            (((size_t)bb * NHD + h) * NSP + n) * HDIM + colp;
                ushort4 o;
                o.x = f2bf(v0); o.y = f2bf(v1); o.z = f2bf(v2); o.w = f2bf(v3);
                *(ushort4*)base = o;
            } else {
                float vv[4] = {v0, v1, v2, v3};
#pragma unroll
                for (int r = 0; r < 4; ++r) {
                    int ch = (m0 - 512) + ml + r;
                    // swizzle within the aligned 64-key block, keyed by ch&7
                    int pos = (n & ~63) + ((((n >> 3) & 7) ^ (ch & 7)) << 3) + (n & 7);
                    v[((size_t)bb * CH + ch) * NSP + pos] = f2bf(vv[r]);
                }
            }
        }
    }
}

// ---------------- attn8: attn7 structure + softmax VALU diet ----------------
// exp2-domain softmax (scale folded into Q by producer), fast P pack
// (+0x8000 round + v_perm pair-pack). Structure identical to verified attn7.
__global__ __launch_bounds__(512, 2) void attn8(const u16* __restrict__ qT,
                                                const u16* __restrict__ kT,
                                                const u16* __restrict__ vN,
                                                u16* __restrict__ aoT) {
    __shared__ u16 Ks[2][2][64][64];   // [khalf][buf][key][ch-swizzled]  32 KB
    __shared__ u16 Vs[2][2][64][64];   // [khalf][buf][ch][key-swizzled]  32 KB
    __shared__ __align__(16) char smem_ps[8 * 32 * 72 * 2];   // Ps / Obuf alias
    __shared__ float Ml[8][2][16][2];
    u16 (*Ps)[32][72] = reinterpret_cast<u16(*)[32][72]>(smem_ps);
    float (*Obuf)[32][68] = reinterpret_cast<float(*)[32][68]>(smem_ps);

    const int h = blockIdx.y, bb = blockIdx.z;
    const int t = threadIdx.x;
    const int wave = t >> 6, lane = t & 63;
    const int qg = wave & 3, kh = wave >> 2;
    const int lq = lane & 15, quad = lane >> 4;
    const int q_lo = blockIdx.x * 128 + qg * 32;

    // Q fragments (swizzled global layout, pre-scaled by QSCALE), two q-tiles
    const int pr = quad ^ (lq & 7);
    const u16* qrow0 = qT + (((size_t)bb * NHD + h) * NSP + q_lo + lq) * HDIM;
    bf16x8 qf[2][2];
    qf[0][0] = *(const bf16x8*)(qrow0 + pr * 8);
    qf[0][1] = *(const bf16x8*)(qrow0 + (pr ^ 4) * 8);
    qf[1][0] = *(const bf16x8*)(qrow0 + 16 * HDIM + pr * 8);
    qf[1][1] = *(const bf16x8*)(qrow0 + 16 * HDIM + (pr ^ 4) * 8);

    const u16* khead = kT + ((size_t)bb * NHD + h) * NSP * (size_t)HDIM;
    const u16* vhead = vN + ((size_t)bb * CH + h * HDIM) * NSP;

    // per-wave staging role: waves 0-3 stage K (kh_s = wave>>1), 4-7 stage V
    const int sK   = (wave < 4);
    const int kh_s = (wave >> 1) & 1;
    const int rbase = (wave & 1) * 32;
    // prologue: DMA tile 0 into buf 0
    {
#pragma unroll
        for (int j = 0; j < 4; ++j) {
            int r8 = rbase + j * 8;
            if (sK) {
                dma16(khead + (size_t)(kh_s * 2048 + r8) * HDIM + lane * 8,
                      &Ks[kh_s][0][r8][0]);
            } else {
                dma16(vhead + (size_t)(r8 + (lane >> 3)) * NSP + kh_s * 2048 + (lane & 7) * 8,
                      &Vs[kh_s][0][r8][0]);
            }
        }
    }

    float m[2] = {-1e30f, -1e30f}, l[2] = {0.f, 0.f};
    f32x4 O[2][4] = {};
    for (int kt = 0; kt < 32; ++kt) {
        const int cur = kt & 1;
        __syncthreads();   // drains this wave's DMA (vmcnt 0) + syncs buffers
        if (kt < 31) {     // DMA tile kt+1 into buf cur^1, overlaps compute
            const int K1 = (kt + 1) * 64;
#pragma unroll
            for (int j = 0; j < 4; ++j) {
                int r8 = rbase + j * 8;
                if (sK) {
                    dma16(khead + (size_t)(kh_s * 2048 + K1 + r8) * HDIM + lane * 8,
                          &Ks[kh_s][cur ^ 1][r8][0]);
                } else {
                    dma16(vhead + (size_t)(r8 + (lane >> 3)) * NSP + kh_s * 2048 + K1 + (lane & 7) * 8,
                          &Vs[kh_s][cur ^ 1][r8][0]);
                }
            }
        }
        // S^T[key][q] (exp2-domain scores) for both q-tiles
        f32x4 st[2][4];
#pragma unroll
        for (int mt = 0; mt < 4; ++mt) {
            bf16x8 a0 = *(const bf16x8*)&Ks[kh][cur][mt * 16 + lq][pr * 8];
            bf16x8 a1 = *(const bf16x8*)&Ks[kh][cur][mt * 16 + lq][(pr ^ 4) * 8];
#pragma unroll
            for (int qt = 0; qt < 2; ++qt) {
                f32x4 acc = {0.f, 0.f, 0.f, 0.f};
                acc = MFMA(a0, qf[qt][0], acc, 0, 0, 0);
                acc = MFMA(a1, qf[qt][1], acc, 0, 0, 0);
                st[qt][mt] = acc;
            }
        }
        // online softmax per q-tile (lane's 16 scores all on one query)
        float alph[2];
#pragma unroll
        for (int qt = 0; qt < 2; ++qt) {
            float mx = m[qt];
#pragma unroll
            for (int mt = 0; mt < 4; ++mt)
#pragma unroll
                for (int r = 0; r < 4; ++r) mx = fmaxf(mx, st[qt][mt][r]);
            mx = fmaxf(mx, __shfl_xor(mx, 16));
            mx = fmaxf(mx, __shfl_xor(mx, 32));
            float alpha = __builtin_amdgcn_exp2f(m[qt] - mx);
            m[qt] = mx;
            float sum = 0.f;
#pragma unroll
            for (int mt = 0; mt < 4; ++mt) {
                float p0 = __builtin_amdgcn_exp2f(st[qt][mt][0] - mx);
                float p1 = __builtin_amdgcn_exp2f(st[qt][mt][1] - mx);
                float p2 = __builtin_amdgcn_exp2f(st[qt][mt][2] - mx);
                float p3 = __builtin_amdgcn_exp2f(st[qt][mt][3] - mx);
                sum += (p0 + p1) + (p2 + p3);
                // fast pack: round-half-up + v_perm pair-pack
                u32 r0 = __float_as_uint(p0) + 0x8000u;
                u32 r1 = __float_as_uint(p1) + 0x8000u;
                u32 r2 = __float_as_uint(p2) + 0x8000u;
                u32 r3 = __float_as_uint(p3) + 0x8000u;
                uint2 pkk;
                pkk.x = __builtin_amdgcn_perm(r1, r0, 0x07060302);
                pkk.y = __builtin_amdgcn_perm(r3, r2, 0x07060302);
                *(uint2*)&Ps[wave][qt * 16 + lq][mt * 16 + quad * 4] = pkk;
            }
            sum += __shfl_xor(sum, 16);
            sum += __shfl_xor(sum, 32);
            l[qt] = l[qt] * alpha + sum;
            alph[qt] = alpha;
        }
        // PV: each Vs frag feeds 2 MFMAs
        bf16x8 pf[2][2];
        pf[0][0] = *(const bf16x8*)&Ps[wave][lq][quad * 8];
        pf[0][1] = *(const bf16x8*)&Ps[wave][lq][32 + quad * 8];
        pf[1][0] = *(const bf16x8*)&Ps[wave][16 + lq][quad * 8];
        pf[1][1] = *(const bf16x8*)&Ps[wave][16 + lq][32 + quad * 8];
#pragma unroll
        for (int mtc = 0; mtc < 4; ++mtc) {
            bf16x8 v0 = *(const bf16x8*)&Vs[kh][cur][mtc * 16 + lq][pr * 8];
            bf16x8 v1 = *(const bf16x8*)&Vs[kh][cur][mtc * 16 + lq][(pr ^ 4) * 8];
#pragma unroll
            for (int qt = 0; qt < 2; ++qt) {
                O[qt][mtc] *= alph[qt];
                O[qt][mtc] = MFMA(v0, pf[qt][0], O[qt][mtc], 0, 0, 0);
                O[qt][mtc] = MFMA(v1, pf[qt][1], O[qt][mtc], 0, 0, 0);
            }
        }
    }
    // ---- 2-way key-half merge (partner = wave^4), exp2 domain ----
    if (lane < 16) {
        Ml[wave][0][lane][0] = m[0]; Ml[wave][0][lane][1] = l[0];
        Ml[wave][1][lane][0] = m[1]; Ml[wave][1][lane][1] = l[1];
    }
    __syncthreads();   // Ml visible; all Ps reads done -> Obuf alias safe
    float gl[2], aw[2];
#pragma unroll
    for (int qt = 0; qt < 2; ++qt) {
        float mA = Ml[qg][qt][lq][0],     lA = Ml[qg][qt][lq][1];
        float mB = Ml[qg + 4][qt][lq][0], lB = Ml[qg + 4][qt][lq][1];
        float gm = fmaxf(mA, mB);
        gl[qt] = lA * __builtin_amdgcn_exp2f(mA - gm)
               + lB * __builtin_amdgcn_exp2f(mB - gm);
        aw[qt] = __builtin_amdgcn_exp2f(m[qt] - gm);
    }
    if (kh == 1) {
#pragma unroll
        for (int qt = 0; qt < 2; ++qt)
#pragma unroll
            for (int mtc = 0; mtc < 4; ++mtc)
                *(f32x4*)&Obuf[qg][qt * 16 + lq][mtc * 16 + quad * 4] = O[qt][mtc] * aw[qt];
    }
    __syncthreads();
    if (kh == 0) {
#pragma unroll
        for (int qt = 0; qt < 2; ++qt) {
            float linv = 1.f / gl[qt];
            u16* op = aoT + ((size_t)bb * NSP + q_lo + qt * 16 + lq) * CH + h * HDIM;
#pragma unroll
            for (int mtc = 0; mtc < 4; ++mtc) {
                f32x4 sres = O[qt][mtc] * aw[qt] +
                             *(const f32x4*)&Obuf[qg][qt * 16 + lq][mtc * 16 + quad * 4];
                ushort4 o;
                o.x = f2bf(sres[0] * linv);
                o.y = f2bf(sres[1] * linv);
                o.z = f2bf(sres[2] * linv);
                o.w = f2bf(sres[3] * linv);
                *(ushort4*)(op + mtc * 16 + quad * 4) = o;
            }
        }
    }
}

// ------- MFMA GEMM proj: out[b][m][n] = sum_c Pw[m][c]*aoT[n][c] + bias + x -------
__global__ __launch_bounds__(256) void gemm_proj(const u16* __restrict__ Aw,
                                                 const float* __restrict__ bias,
                                                 const u16* __restrict__ aoT,
                                                 const float* __restrict__ xres,
                                                 float* __restrict__ out) {
    const int n0 = blockIdx.x * 64, m0 = blockIdx.y * 64, bb = blockIdx.z;
    const int wave = threadIdx.x >> 6, lane = threadIdx.x & 63;
    const int lq = lane & 15, quad = lane >> 4;
    const int wm = (wave >> 1) * 32, wn = (wave & 1) * 32;
    f32x4 acc[2][2] = {};
    const u16* ap = Aw + (size_t)(m0 + wm + lq) * CH + quad * 8;
    const u16* bp = aoT + ((size_t)bb * NSP + n0 + wn + lq) * CH + quad * 8;
#pragma unroll
    for (int k0 = 0; k0 < CH; k0 += 32) {
        bf16x8 a0 = *(const bf16x8*)(ap + k0);
        bf16x8 a1 = *(const bf16x8*)(ap + 16 * CH + k0);
        bf16x8 b0 = *(const bf16x8*)(bp + k0);
        bf16x8 b1 = *(const bf16x8*)(bp + 16 * CH + k0);
        acc[0][0] = MFMA(a0, b0, acc[0][0], 0, 0, 0);
        acc[0][1] = MFMA(a0, b1, acc[0][1], 0, 0, 0);
        acc[1][0] = MFMA(a1, b0, acc[1][0], 0, 0, 0);
        acc[1][1] = MFMA(a1, b1, acc[1][1], 0, 0, 0);
    }
#pragma unroll
    for (int im = 0; im < 2; ++im) {
        int ml = wm + im * 16 + quad * 4;
        float4 bs = *(const float4*)(bias + m0 + ml);
        float bsv[4] = {bs.x, bs.y, bs.z, bs.w};
#pragma unroll
        for (int in = 0; in < 2; ++in) {
            int n = n0 + wn + in * 16 + lq;
            f32x4 a = acc[im][in];
#pragma unroll
            for (int r = 0; r < 4; ++r) {
                size_t idx = ((size_t)bb * CH + m0 + ml + r) * NSP + n;
                out[idx] = a[r] + bsv[r] + xres[idx];
            }
        }
    }
}

extern "C" void kernel_launch(void* const* d_in, const int* in_sizes, int n_in,
                              void* d_out, int out_size, void* d_ws, size_t ws_size,
                              hipStream_t stream) {
    const float* x      = (const float*)d_in[0];
    const float* norm_w = (const float*)d_in[1];
    const float* norm_b = (const float*)d_in[2];
    const float* qkv_w  = (const float*)d_in[3];
    const float* qkv_b  = (const float*)d_in[4];
    const float* proj_w = (const float*)d_in[5];
    const float* proj_b = (const float*)d_in[6];
    float* out = (float*)d_out;

    char* w = (char*)d_ws;
    float* partial = (float*)w;                       // 4 KB (16x16x2 fp32)
    u16* wqb = (u16*)(w + 4096);                      // 384 KB (768x256 bf16)
    u16* wpb = (u16*)(w + 4096 + 393216);             // 128 KB (256x256 bf16)
    u16* xnT = (u16*)(w + 528384);                    // 4 MB [b][n][c] (aliased by aoT)
    u16* qT  = (u16*)(w + 528384 + 4194304);          // 4 MB [b][h][n][64] swizzled, pre-scaled
    u16* kT  = (u16*)(w + 528384 + 2 * 4194304);      // 4 MB [b][h][n][64] swizzled
    u16* v   = (u16*)(w + 528384 + 3 * 4194304);      // 4 MB [b][c][n] swizzled blocks
    u16* aoT = xnT;                                   // xnT dead after gemm_qkv

    wconv2<<<dim3(256), 256, 0, stream>>>(qkv_w, proj_w, wqb, wpb);
    gn_part<<<dim3(NB * NG, 16), 256, 0, stream>>>(x, partial);
    gn_apply_t<<<dim3(NSP / 64, CH / 64, NB), 256, 0, stream>>>(
        x, partial, norm_w, norm_b, xnT);
    gemm_qkv<<<dim3(NSP / 64, (3 * CH) / 64, NB), 256, 0, stream>>>(
        wqb, qkv_b, xnT, qT, kT, v);
    attn8<<<dim3(NSP / 128, NHD, NB), 512, 0, stream>>>(qT, kT, v, aoT);
    gemm_proj<<<dim3(NSP / 64, CH / 64, NB), 256, 0, stream>>>(
        wpb, proj_b, aoT, x, out);
}